// Round 4
// baseline (151.118 us; speedup 1.0000x reference)
//
#include <hip/hip_runtime.h>
#include <hip/hip_bf16.h>
#include <math.h>

#define NB 4096    // batch
#define NN 8192    // N = B * n_views
#define DD 128     // feature dim
#define NCLS 100   // label values 0..99
#define NSPLIT 32  // j-splits in k_main (256 cols each)

constexpr float INV_T = 14.285714285714286f;      // 1/0.07 (also the subtracted row max)
constexpr float EC1   = 20.609929155556620f;      // INV_T * log2(e)
constexpr float EC0   = -20.609929155556620f;     // -INV_T * log2(e)
constexpr float LN2   = 0.6931471805599453f;

typedef __attribute__((ext_vector_type(8))) short bf16x8;
typedef __attribute__((ext_vector_type(4))) float f32x4;

__device__ __forceinline__ float bf2f(ushort u) {
    union { unsigned int i; float f; } v; v.i = ((unsigned int)u) << 16; return v.f;
}

// ---- kernel 1: L2-normalize rows -> bf16, fused class-sum/count atomics ----
// One wave per row. S (zeroed by memset beforehand) gets the fp32-normalized
// row scattered by label; counts gets +1 per batch entry (view 0 only).
__global__ __launch_bounds__(256) void k_normalize(const float* __restrict__ feat,
                                                   __hip_bfloat16* __restrict__ fb,
                                                   const int* __restrict__ labels,
                                                   float* __restrict__ S,
                                                   int* __restrict__ counts) {
    const int r    = (blockIdx.x * 256 + threadIdx.x) >> 6;
    const int lane = threadIdx.x & 63;
    const float2 v = ((const float2*)(feat + (size_t)r * DD))[lane];
    float ss = v.x * v.x + v.y * v.y;
#pragma unroll
    for (int off = 1; off < 64; off <<= 1) ss += __shfl_xor(ss, off, 64);
    const float scale = 1.0f / fmaxf(sqrtf(ss), 1e-12f);
    const float x = v.x * scale, y = v.y * scale;
    __hip_bfloat162 h2;
    h2.x = __float2bfloat16(x);
    h2.y = __float2bfloat16(y);
    ((__hip_bfloat162*)(fb + (size_t)r * DD))[lane] = h2;

    const int c = labels[r & (NB - 1)];           // wave-uniform scalar load
    atomicAdd(&S[c * DD + 2 * lane],     x);
    atomicAdd(&S[c * DD + 2 * lane + 1], y);
    if (lane == 0 && r < NB) atomicAdd(&counts[c], 1);
}

// ---- kernel 2: F*F^T with fused row-sum of exp ----
// Wave job: 32 rows (2 tiles of 16) x 256 cols (16 j-tiles), register
// double-buffered B. 4 waves/block share the j-range (B hits L1).
// Grid MUST be (NN/32 rowgroups) * NSPLIT / 4 waves = 2048 blocks.
// Epilogue per element: fma + v_exp + add; no masks/labels/self-check
// (self term subtracted analytically in k_final).
__global__ __launch_bounds__(256) void k_main(const ushort* __restrict__ fb,
                                              float* __restrict__ g_se2) {
    const int lane = threadIdx.x & 63;
    const int w    = threadIdx.x >> 6;
    const int js   = blockIdx.x & (NSPLIT - 1);          // shared by the block's 4 waves
    const int rg   = (blockIdx.x >> 5) * 4 + w;          // 0..255
    const int i0   = rg * 32;
    const int j0   = js * 256;
    const int q    = lane >> 4;
    const int n15  = lane & 15;

    // A fragments: 2 row-tiles x 4 k-tiles (32 regs), resident whole kernel
    bf16x8 afrag[2][4];
#pragma unroll
    for (int tt = 0; tt < 2; ++tt) {
        const ushort* rp = fb + (size_t)(i0 + tt * 16 + n15) * DD + q * 8;
#pragma unroll
        for (int kt = 0; kt < 4; ++kt)
            afrag[tt][kt] = *(const bf16x8*)(rp + kt * 32);
    }

    float a_se[8] = {};

    bf16x8 cur[4], nxt[4];
    {
        const ushort* bp = fb + (size_t)(j0 + n15) * DD + q * 8;
#pragma unroll
        for (int kt = 0; kt < 4; ++kt) cur[kt] = *(const bf16x8*)(bp + kt * 32);
    }

#pragma unroll 2
    for (int it = 0; it < 16; ++it) {
        // prefetch next j-tile (wraps to tile 0 on last iter; harmless)
        const ushort* bpn = fb + (size_t)(j0 + (((it + 1) & 15) << 4) + n15) * DD + q * 8;
#pragma unroll
        for (int kt = 0; kt < 4; ++kt) nxt[kt] = *(const bf16x8*)(bpn + kt * 32);

#pragma unroll
        for (int tt = 0; tt < 2; ++tt) {
            f32x4 a = {0.f, 0.f, 0.f, 0.f};
#pragma unroll
            for (int kt = 0; kt < 4; ++kt)
                a = __builtin_amdgcn_mfma_f32_16x16x32_bf16(afrag[tt][kt], cur[kt], a, 0, 0, 0);
#pragma unroll
            for (int r = 0; r < 4; ++r)
                a_se[tt * 4 + r] += __builtin_amdgcn_exp2f(fmaf(a[r], EC1, EC0));
        }
#pragma unroll
        for (int kt = 0; kt < 4; ++kt) cur[kt] = nxt[kt];
    }

    // lanes n15=0..15 within a quad hold the same rows; reduce, plain store
    // (each (js,row) slot written by exactly one wave -> no atomics/memset)
#pragma unroll
    for (int s = 0; s < 8; ++s) {
        float v = a_se[s];
#pragma unroll
        for (int off = 1; off < 16; off <<= 1) v += __shfl_xor(v, off, 64);
        if (n15 == 0)
            g_se2[js * NN + i0 + (s >> 2) * 16 + q * 4 + (s & 3)] = v;
    }
}

// ---- kernel 3: per-row loss -> per-block partial (1 wave/block, 128 blocks) ----
__global__ __launch_bounds__(64) void k_final(const ushort* __restrict__ fb,
                                              const int* __restrict__ labels,
                                              const float* __restrict__ g_se2,
                                              const float* __restrict__ S,
                                              const int* __restrict__ counts,
                                              float* __restrict__ partial) {
    const int r = blockIdx.x * 64 + threadIdx.x;
    const int c = labels[r & (NB - 1)];
    const ushort* fp = fb + (size_t)r * DD;
    const float*  sp = S + c * DD;
    float s1 = 0.0f, s2 = 0.0f;   // dot(f_i, S_c), dot(f_i, f_i) from the bf16 row
#pragma unroll
    for (int k = 0; k < DD; k += 4) {
        ushort4 u = *(const ushort4*)(fp + k);
        float4 sv = *(const float4*)(sp + k);
        float x0 = bf2f(u.x), x1 = bf2f(u.y), x2 = bf2f(u.z), x3 = bf2f(u.w);
        s1 = fmaf(x0, sv.x, fmaf(x1, sv.y, fmaf(x2, sv.z, fmaf(x3, sv.w, s1))));
        s2 = fmaf(x0, x0, fmaf(x1, x1, fmaf(x2, x2, fmaf(x3, x3, s2))));
    }
    float sum32 = 0.0f;
#pragma unroll
    for (int t = 0; t < NSPLIT; ++t) sum32 += g_se2[t * NN + r];

    float selfexp = __builtin_amdgcn_exp2f(fmaf(s2, EC1, EC0)); // matches epilogue's self term
    float se   = sum32 - selfexp;                               // sum_{j!=i} exp(l_ij - M)
    float cnt  = (float)(2 * counts[c] - 1);
    float possum = INV_T * (s1 - s2) - cnt * INV_T;
    float lg   = __builtin_amdgcn_logf(se + 1e-12f) * LN2;
    float mlpp = (possum - cnt * lg) / fmaxf(cnt, 1.0f);
    float v = -mlpp * (1.0f / (float)NN);
#pragma unroll
    for (int off = 1; off < 64; off <<= 1) v += __shfl_xor(v, off, 64);
    if (threadIdx.x == 0) partial[blockIdx.x] = v;
}

// ---- kernel 4: sum 128 partials -> out ----
__global__ void k_sum(const float* __restrict__ partial, float* __restrict__ out) {
    float v = partial[threadIdx.x];
#pragma unroll
    for (int off = 1; off < 64; off <<= 1) v += __shfl_xor(v, off, 64);
    __shared__ float sred[2];
    if ((threadIdx.x & 63) == 0) sred[threadIdx.x >> 6] = v;
    __syncthreads();
    if (threadIdx.x == 0) out[0] = sred[0] + sred[1];
}

extern "C" void kernel_launch(void* const* d_in, const int* in_sizes, int n_in,
                              void* d_out, int out_size, void* d_ws, size_t ws_size,
                              hipStream_t stream) {
    const float* feat  = (const float*)d_in[0];
    const int* labels  = (const int*)d_in[1];
    float* out         = (float*)d_out;
    char* ws           = (char*)d_ws;

    __hip_bfloat16* fb = (__hip_bfloat16*)ws;                        // 2 MB
    float* g_se2 = (float*)(ws + (size_t)2 * 1024 * 1024);           // 1 MB [NSPLIT][NN]
    float* S     = (float*)(ws + (size_t)3 * 1024 * 1024);           // 100*128 f32
    int*   counts= (int*)(S + NCLS * DD);                            // 100 i32
    float* partial = (float*)(ws + (size_t)3 * 1024 * 1024 + 64 * 1024); // 128 f32

    hipMemsetAsync(S, 0, (NCLS * DD + NCLS) * sizeof(float), stream);
    k_normalize<<<NN / 4, 256, 0, stream>>>(feat, fb, labels, S, counts);
    // (NN/32) row-groups * NSPLIT j-splits / 4 waves-per-block = 2048 blocks
    k_main<<<(NN / 32) * NSPLIT / 4, 256, 0, stream>>>((const ushort*)fb, g_se2);
    k_final<<<NN / 64, 64, 0, stream>>>((const ushort*)fb, labels, g_se2, S, counts, partial);
    k_sum<<<1, 128, 0, stream>>>(partial, out);
}

// Round 5
// 99.342 us; speedup vs baseline: 1.5212x; 1.5212x over previous
//
#include <hip/hip_runtime.h>
#include <hip/hip_bf16.h>
#include <math.h>

#define NB 4096     // batch
#define NN 8192     // N = B * n_views
#define DD 128      // feature dim
#define NSPLIT 16   // j-splits; 512 cols per block
#define CHUNK 64    // cols per LDS-staged chunk
#define NCHUNK 8    // 512 / 64

constexpr float INV_T = 14.285714285714286f;   // 1/0.07 (= subtracted row max M)
constexpr float EC1   = 20.609929155556620f;   // INV_T * log2(e)
constexpr float EC0   = -20.609929155556620f;  // -INV_T * log2(e)
constexpr float LN2   = 0.6931471805599453f;

typedef __attribute__((ext_vector_type(8))) short bf16x8;
typedef __attribute__((ext_vector_type(4))) float f32x4;

__device__ __forceinline__ float bf2f(ushort u) {
    union { unsigned int i; float f; } v; v.i = ((unsigned int)u) << 16; return v.f;
}

// ---- kernel 1: L2-normalize rows -> bf16; also emit bf16 self-dot per row ----
__global__ __launch_bounds__(256) void k_norm(const float* __restrict__ feat,
                                              ushort* __restrict__ fb,
                                              float* __restrict__ selfdot) {
    const int r    = (blockIdx.x * 256 + threadIdx.x) >> 6;   // one wave per row
    const int lane = threadIdx.x & 63;
    const float2 v = ((const float2*)(feat + (size_t)r * DD))[lane];
    float ss = v.x * v.x + v.y * v.y;
#pragma unroll
    for (int off = 1; off < 64; off <<= 1) ss += __shfl_xor(ss, off, 64);
    const float scale = 1.0f / fmaxf(sqrtf(ss), 1e-12f);
    __hip_bfloat162 h2;
    h2.x = __float2bfloat16(v.x * scale);
    h2.y = __float2bfloat16(v.y * scale);
    ((__hip_bfloat162*)(fb + (size_t)r * DD))[lane] = h2;
    // self-dot of the QUANTIZED row (matches what the MFMA diagonal computes)
    const float xb = bf2f(((ushort2*)&h2)->x), yb = bf2f(((ushort2*)&h2)->y);
    float s2 = xb * xb + yb * yb;
#pragma unroll
    for (int off = 1; off < 64; off <<= 1) s2 += __shfl_xor(s2, off, 64);
    if (lane == 0) selfdot[r] = s2;
}

// stage one 64-col chunk's B-fragments into LDS, fragment-major.
// Wave w stages j-tile jt=w (4 kt instrs). LDS dst is wave-uniform base +
// lane*16 (HW rule); the per-lane GLOBAL address does the fragment gather.
__device__ __forceinline__ void stage_chunk(const ushort* __restrict__ fb, ushort* sbuf,
                                            int jb, int w, int n15, int q) {
    const ushort* g = fb + (size_t)(jb + w * 16 + n15) * DD + q * 8;
#pragma unroll
    for (int kt = 0; kt < 4; ++kt)
        __builtin_amdgcn_global_load_lds(
            (const __attribute__((address_space(1))) void*)(g + kt * 32),
            (__attribute__((address_space(3))) void*)(sbuf + (w * 4 + kt) * 512),
            16, 0, 0);
}

// ---- kernel 2: F*F^T, B double-buffered in LDS, fused exp/pos/cnt epilogue ----
// Block: 128 rows x 512 cols. Wave: 32 rows (2 tiles). 1024 blocks, 4 blk/CU.
__global__ __launch_bounds__(256, 4) void k_main(const ushort* __restrict__ fb,
                                                 const int* __restrict__ labels,
                                                 float* __restrict__ g_se,
                                                 float* __restrict__ g_ps,
                                                 float* __restrict__ g_ct) {
    __shared__ ushort sB[2][CHUNK * DD];   // 2 x 16 KB, fragment-major
    __shared__ int slab[512];              // labels of this block's col range

    const int tid  = threadIdx.x;
    const int lane = tid & 63;
    const int w    = tid >> 6;
    const int rb   = blockIdx.x >> 4;          // 0..63 row-block
    const int js   = blockIdx.x & (NSPLIT - 1);
    const int i0   = rb * 128 + w * 32;
    const int jb0  = js * 512;
    const int q    = lane >> 4;
    const int n15  = lane & 15;

    slab[tid]       = labels[(jb0 + tid) & (NB - 1)];
    slab[tid + 256] = labels[(jb0 + tid + 256) & (NB - 1)];

    // A fragments: 2 row-tiles x 4 kt (32 regs), resident whole kernel
    bf16x8 afrag[2][4];
#pragma unroll
    for (int tt = 0; tt < 2; ++tt) {
        const ushort* rp = fb + (size_t)(i0 + tt * 16 + n15) * DD + q * 8;
#pragma unroll
        for (int kt = 0; kt < 4; ++kt) afrag[tt][kt] = *(const bf16x8*)(rp + kt * 32);
    }
    // labels of this lane's 8 accumulator rows (C/D map: row = q*4+r)
    int labi[8];
#pragma unroll
    for (int tt = 0; tt < 2; ++tt)
#pragma unroll
        for (int r = 0; r < 4; ++r)
            labi[tt * 4 + r] = labels[(i0 + tt * 16 + q * 4 + r) & (NB - 1)];

    float a_se[8] = {}, a_ps[8] = {}, a_ct[8] = {};

    stage_chunk(fb, &sB[0][0], jb0, w, n15, q);
    __syncthreads();

    for (int c = 0; c < NCHUNK; ++c) {
        if (c + 1 < NCHUNK)
            stage_chunk(fb, &sB[(c + 1) & 1][0], jb0 + (c + 1) * CHUNK, w, n15, q);
        const ushort* sb = &sB[c & 1][0];
        const int crel = c * CHUNK;
#pragma unroll
        for (int jt = 0; jt < 4; ++jt) {
            bf16x8 bf[4];
#pragma unroll
            for (int kt = 0; kt < 4; ++kt)
                bf[kt] = *(const bf16x8*)(sb + (jt * 4 + kt) * 512 + lane * 8); // conflict-free
            const int labj = slab[crel + jt * 16 + n15];
            f32x4 a0 = {0.f, 0.f, 0.f, 0.f}, a1 = {0.f, 0.f, 0.f, 0.f};
#pragma unroll
            for (int kt = 0; kt < 4; ++kt) {
                a0 = __builtin_amdgcn_mfma_f32_16x16x32_bf16(afrag[0][kt], bf[kt], a0, 0, 0, 0);
                a1 = __builtin_amdgcn_mfma_f32_16x16x32_bf16(afrag[1][kt], bf[kt], a1, 0, 0, 0);
            }
#pragma unroll
            for (int r = 0; r < 4; ++r) {
                const float d0 = a0[r], d1 = a1[r];
                a_se[r]     += __builtin_amdgcn_exp2f(fmaf(d0, EC1, EC0));
                a_se[4 + r] += __builtin_amdgcn_exp2f(fmaf(d1, EC1, EC0));
                const bool m0 = (labi[r] == labj), m1 = (labi[4 + r] == labj);
                a_ps[r]     += m0 ? d0 : 0.0f;   // raw dot; scaled/shifted in k_final
                a_ps[4 + r] += m1 ? d1 : 0.0f;
                a_ct[r]     += m0 ? 1.0f : 0.0f;
                a_ct[4 + r] += m1 ? 1.0f : 0.0f;
            }
        }
        __syncthreads();
    }

    // 16 lanes per quad share the same rows; reduce, single plain store each
#pragma unroll
    for (int s = 0; s < 8; ++s) {
        float v1 = a_se[s], v2 = a_ps[s], v3 = a_ct[s];
#pragma unroll
        for (int off = 1; off < 16; off <<= 1) {
            v1 += __shfl_xor(v1, off, 64);
            v2 += __shfl_xor(v2, off, 64);
            v3 += __shfl_xor(v3, off, 64);
        }
        if (n15 == 0) {
            const int row = i0 + (s >> 2) * 16 + q * 4 + (s & 3);
            g_se[js * NN + row] = v1;
            g_ps[js * NN + row] = v2;
            g_ct[js * NN + row] = v3;
        }
    }
}

// ---- kernel 3: per-row loss (analytic self-term removal) -> atomic mean ----
__global__ __launch_bounds__(256) void k_final(const float* __restrict__ g_se,
                                               const float* __restrict__ g_ps,
                                               const float* __restrict__ g_ct,
                                               const float* __restrict__ selfdot,
                                               float* __restrict__ out) {
    const int r = blockIdx.x * 256 + threadIdx.x;
    float se = 0.f, ps = 0.f, ct = 0.f;
#pragma unroll
    for (int t = 0; t < NSPLIT; ++t) {
        se += g_se[t * NN + r];
        ps += g_ps[t * NN + r];
        ct += g_ct[t * NN + r];
    }
    const float sd = selfdot[r];
    se -= __builtin_amdgcn_exp2f(fmaf(sd, EC1, EC0));  // drop diagonal from sumexp
    ct -= 1.0f;                                        // drop diagonal from positives
    const float possum = INV_T * (ps - sd - ct);       // sum_pos (l_ij - M)
    const float lg  = __builtin_amdgcn_logf(se + 1e-12f) * LN2;
    const float mlpp = (possum - ct * lg) / fmaxf(ct, 1.0f);
    float v = -mlpp * (1.0f / (float)NN);
#pragma unroll
    for (int off = 1; off < 64; off <<= 1) v += __shfl_xor(v, off, 64);
    __shared__ float sred[4];
    if ((threadIdx.x & 63) == 0) sred[threadIdx.x >> 6] = v;
    __syncthreads();
    if (threadIdx.x == 0) atomicAdd(out, sred[0] + sred[1] + sred[2] + sred[3]);
}

extern "C" void kernel_launch(void* const* d_in, const int* in_sizes, int n_in,
                              void* d_out, int out_size, void* d_ws, size_t ws_size,
                              hipStream_t stream) {
    const float* feat = (const float*)d_in[0];
    const int* labels = (const int*)d_in[1];
    float* out        = (float*)d_out;
    char* ws          = (char*)d_ws;

    ushort* fb      = (ushort*)ws;                                   // 2 MB
    float* g_se     = (float*)(ws + (size_t)2 * 1024 * 1024);        // 512 KB [16][NN]
    float* g_ps     = g_se + NSPLIT * NN;                            // 512 KB
    float* g_ct     = g_ps + NSPLIT * NN;                            // 512 KB
    float* selfdot  = g_ct + NSPLIT * NN;                            // 32 KB

    hipMemsetAsync(out, 0, sizeof(float), stream);
    k_norm<<<NN / 4, 256, 0, stream>>>(feat, fb, selfdot);
    k_main<<<64 * NSPLIT, 256, 0, stream>>>(fb, labels, g_se, g_ps, g_ct);
    k_final<<<NN / 256, 256, 0, stream>>>(g_se, g_ps, g_ct, selfdot, out);
}